// Round 1
// baseline (195.882 us; speedup 1.0000x reference)
//
#include <hip/hip_runtime.h>

// YOLO loss: N=4096 images, S=14 grid, B=2 boxes, NC=20 classes.
// Memory-bound reduction: ~174 MB in -> 5 floats out.

#define GS 14
#define NB 2
#define NCLS 20

// ws layout (floats): [0]=reg, [1]=contain, [2]=noobj, [3]=cls, [4]=mask-format flag (as int)

__global__ void yolo_init_kernel(const unsigned char* __restrict__ mask_bytes,
                                 int ncells, float* __restrict__ acc) {
    // Single block. Zero accumulators and sniff the mask buffer's dtype:
    //   fmt=0: int32 (bytes at k%4!=0 are all zero, all bytes <=1)
    //   fmt=1: uint8/bool (some byte at k%4!=0 nonzero, all bytes <=1)
    //   fmt=2: float32 (some byte value > 1, e.g. 0x3f/0x80 of 1.0f)
    __shared__ int s_nz_off, s_gt1;
    if (threadIdx.x == 0) { s_nz_off = 0; s_gt1 = 0; }
    __syncthreads();
    int nscan = 16384;
    if (ncells < nscan) nscan = ncells;  // bytes; safe for every candidate layout
    for (int i = threadIdx.x; i < nscan; i += blockDim.x) {
        unsigned char v = mask_bytes[i];
        if (v > 1) s_gt1 = 1;                  // racy write of 1: fine
        if ((i & 3) != 0 && v != 0) s_nz_off = 1;
    }
    __syncthreads();
    if (threadIdx.x < 4) acc[threadIdx.x] = 0.0f;
    if (threadIdx.x == 0) {
        int fmt = s_gt1 ? 2 : (s_nz_off ? 1 : 0);
        ((int*)acc)[4] = fmt;
    }
}

__launch_bounds__(256)
__global__ void yolo_loss_kernel(const float* __restrict__ pred,
                                 const float* __restrict__ tbox,
                                 const float* __restrict__ tcls,
                                 const void* __restrict__ mask,
                                 float* __restrict__ acc,
                                 int ncells) {
    const int fmt = ((const int*)acc)[4];
    const float invS = 1.0f / (float)GS;

    float reg = 0.0f, cont = 0.0f, noobj = 0.0f, cls = 0.0f;

    for (int cell = blockIdx.x * blockDim.x + threadIdx.x; cell < ncells;
         cell += gridDim.x * blockDim.x) {
        bool m;
        if (fmt == 2)      m = ((const float*)mask)[cell] != 0.0f;
        else if (fmt == 1) m = ((const unsigned char*)mask)[cell] != 0;
        else               m = ((const int*)mask)[cell] != 0;

        const float* p = pred + (size_t)cell * (NB * 5 + NCLS);

        if (m) {
            const float* tb = tbox + (size_t)cell * 4;
            const float* tc = tcls + (size_t)cell * NCLS;
            const float tx = tb[0], ty = tb[1], tw = tb[2], th = tb[3];

            // target xyxy
            const float tcx = tx * invS, tcy = ty * invS;
            const float t_x1 = tcx - 0.5f * tw, t_y1 = tcy - 0.5f * th;
            const float t_x2 = tcx + 0.5f * tw, t_y2 = tcy + 0.5f * th;
            const float ta = (t_x2 - t_x1) * (t_y2 - t_y1);

            // box 0
            const float b0x = p[0], b0y = p[1], b0w = p[2], b0h = p[3], b0c = p[4];
            // box 1
            const float b1x = p[5], b1y = p[6], b1w = p[7], b1h = p[8], b1c = p[9];

            float iou0, iou1;
            {
                const float cx = b0x * invS, cy = b0y * invS;
                const float x1 = cx - 0.5f * b0w, y1 = cy - 0.5f * b0h;
                const float x2 = cx + 0.5f * b0w, y2 = cy + 0.5f * b0h;
                const float iw = fmaxf(fminf(x2, t_x2) - fmaxf(x1, t_x1), 0.0f);
                const float ih = fmaxf(fminf(y2, t_y2) - fmaxf(y1, t_y1), 0.0f);
                const float inter = iw * ih;
                const float pa = (x2 - x1) * (y2 - y1);
                iou0 = inter / (pa + ta - inter);
            }
            {
                const float cx = b1x * invS, cy = b1y * invS;
                const float x1 = cx - 0.5f * b1w, y1 = cy - 0.5f * b1h;
                const float x2 = cx + 0.5f * b1w, y2 = cy + 0.5f * b1h;
                const float iw = fmaxf(fminf(x2, t_x2) - fmaxf(x1, t_x1), 0.0f);
                const float ih = fmaxf(fminf(y2, t_y2) - fmaxf(y1, t_y1), 0.0f);
                const float inter = iw * ih;
                const float pa = (x2 - x1) * (y2 - y1);
                iou1 = inter / (pa + ta - inter);
            }

            // jnp.argmax picks the FIRST max on ties -> strict '>' selects box 1.
            const bool sel1 = iou1 > iou0;
            const float biou = fmaxf(iou0, iou1);
            const float rx = sel1 ? b1x : b0x;
            const float ry = sel1 ? b1y : b0y;
            const float rw = sel1 ? b1w : b0w;
            const float rh = sel1 ? b1h : b0h;
            const float rc = sel1 ? b1c : b0c;

            const float d0 = rx - tx, d1 = ry - ty;
            const float d2 = sqrtf(rw) - sqrtf(tw);
            const float d3 = sqrtf(rh) - sqrtf(th);
            reg += d0 * d0 + d1 * d1 + d2 * d2 + d3 * d3;

            const float dc = rc - biou;
            cont += dc * dc;

            #pragma unroll
            for (int c = 0; c < NCLS; ++c) {
                const float d = p[NB * 5 + c] - tc[c];
                cls += d * d;
            }
        } else {
            const float c0 = p[4], c1 = p[9];
            noobj += c0 * c0 + c1 * c1;
        }
    }

    // wave64 reduce
    #pragma unroll
    for (int off = 32; off > 0; off >>= 1) {
        reg   += __shfl_down(reg, off);
        cont  += __shfl_down(cont, off);
        noobj += __shfl_down(noobj, off);
        cls   += __shfl_down(cls, off);
    }

    __shared__ float sred[4][4];  // [wave][counter]
    const int wave = threadIdx.x >> 6;
    const int lane = threadIdx.x & 63;
    if (lane == 0) {
        sred[wave][0] = reg; sred[wave][1] = cont;
        sred[wave][2] = noobj; sred[wave][3] = cls;
    }
    __syncthreads();
    if (threadIdx.x == 0) {
        float r = 0, c = 0, no = 0, cl = 0;
        const int nwaves = (blockDim.x + 63) >> 6;
        for (int w = 0; w < nwaves; ++w) {
            r += sred[w][0]; c += sred[w][1]; no += sred[w][2]; cl += sred[w][3];
        }
        atomicAdd(&acc[0], r);
        atomicAdd(&acc[1], c);
        atomicAdd(&acc[2], no);
        atomicAdd(&acc[3], cl);
    }
}

__global__ void yolo_finalize_kernel(const float* __restrict__ acc,
                                     float* __restrict__ out, float inv_n) {
    const float reg = acc[0], cont = acc[1], noobj = acc[2], cls = acc[3];
    const float total = (5.0f * reg + 0.5f * noobj + cont + cls) * inv_n;
    out[0] = total;
    out[1] = reg;
    out[2] = cont;
    out[3] = noobj;
    out[4] = cls;
}

extern "C" void kernel_launch(void* const* d_in, const int* in_sizes, int n_in,
                              void* d_out, int out_size, void* d_ws, size_t ws_size,
                              hipStream_t stream) {
    const float* pred = (const float*)d_in[0];
    const float* tbox = (const float*)d_in[1];
    const float* tcls = (const float*)d_in[2];
    const void*  mask = d_in[3];
    float* acc = (float*)d_ws;
    float* out = (float*)d_out;

    const int ncells = in_sizes[3];                 // N * S * S
    const int n_img  = ncells / (GS * GS);          // N
    const float inv_n = 1.0f / (float)n_img;

    yolo_init_kernel<<<1, 256, 0, stream>>>((const unsigned char*)mask, ncells, acc);

    const int block = 256;
    const int grid = (ncells + block - 1) / block;  // 3136 blocks
    yolo_loss_kernel<<<grid, block, 0, stream>>>(pred, tbox, tcls, mask, acc, ncells);

    yolo_finalize_kernel<<<1, 1, 0, stream>>>(acc, out, inv_n);
}

// Round 2
// 49.073 us; speedup vs baseline: 3.9917x; 3.9917x over previous
//
#include <hip/hip_runtime.h>

// YOLO loss: N=4096 images, S=14 grid, B=2 boxes, NC=20 classes.
// ncells = N*S*S = 802816 = 2^14 * 49.
// Latency-bound reduction: fix = MLP (2 cells/thread, 15x dwordx4 up-front),
// spread atomics across 64 cache lines, tiny finalize kernel.

#define GS 14
#define NB 2
#define NCLS 20
#define NPRED 30          // floats per cell in pred
#define CELLS_PER_THREAD 2
#define BLOCK 256
#define NSLOTS 64         // partial-sum slots, 64B apart
#define SLOT_STRIDE 16    // floats

// ws layout (floats):
//   [0]            : mask-format flag (as int)
//   [16 + s*16 +k] : partial sums, slot s in [0,64), counter k in [0,4)

__global__ void yolo_init_kernel(const unsigned char* __restrict__ mask_bytes,
                                 int ncells, float* __restrict__ ws) {
    // Single block: zero partial slots and sniff mask dtype.
    //   fmt=0: int32, fmt=1: uint8/bool, fmt=2: float32
    __shared__ int s_nz_off, s_gt1;
    if (threadIdx.x == 0) { s_nz_off = 0; s_gt1 = 0; }
    __syncthreads();
    int nscan = 16384;
    if (ncells < nscan) nscan = ncells;
    for (int i = threadIdx.x; i < nscan; i += blockDim.x) {
        unsigned char v = mask_bytes[i];
        if (v > 1) s_gt1 = 1;
        if ((i & 3) != 0 && v != 0) s_nz_off = 1;
    }
    __syncthreads();
    for (int i = threadIdx.x; i < NSLOTS * SLOT_STRIDE; i += blockDim.x)
        ws[16 + i] = 0.0f;
    if (threadIdx.x == 0) {
        int fmt = s_gt1 ? 2 : (s_nz_off ? 1 : 0);
        ((int*)ws)[0] = fmt;
    }
}

template <int CB>
__device__ __forceinline__ void cell_compute(const float (&v)[60],
                                             const float* __restrict__ tbox,
                                             const float* __restrict__ tcls,
                                             int cell, bool m,
                                             float& reg, float& cont,
                                             float& noobj, float& cls) {
    const float invS = 1.0f / (float)GS;
    if (m) {
        const float4 tb4 = *reinterpret_cast<const float4*>(tbox + (size_t)cell * 4);
        const float tx = tb4.x, ty = tb4.y, tw = tb4.z, th = tb4.w;

        const float tcx = tx * invS, tcy = ty * invS;
        const float t_x1 = tcx - 0.5f * tw, t_y1 = tcy - 0.5f * th;
        const float t_x2 = tcx + 0.5f * tw, t_y2 = tcy + 0.5f * th;
        const float ta = (t_x2 - t_x1) * (t_y2 - t_y1);

        const float b0x = v[CB + 0], b0y = v[CB + 1], b0w = v[CB + 2], b0h = v[CB + 3], b0c = v[CB + 4];
        const float b1x = v[CB + 5], b1y = v[CB + 6], b1w = v[CB + 7], b1h = v[CB + 8], b1c = v[CB + 9];

        float iou0, iou1;
        {
            const float cx = b0x * invS, cy = b0y * invS;
            const float x1 = cx - 0.5f * b0w, y1 = cy - 0.5f * b0h;
            const float x2 = cx + 0.5f * b0w, y2 = cy + 0.5f * b0h;
            const float iw = fmaxf(fminf(x2, t_x2) - fmaxf(x1, t_x1), 0.0f);
            const float ih = fmaxf(fminf(y2, t_y2) - fmaxf(y1, t_y1), 0.0f);
            const float inter = iw * ih;
            const float pa = (x2 - x1) * (y2 - y1);
            iou0 = inter / (pa + ta - inter);
        }
        {
            const float cx = b1x * invS, cy = b1y * invS;
            const float x1 = cx - 0.5f * b1w, y1 = cy - 0.5f * b1h;
            const float x2 = cx + 0.5f * b1w, y2 = cy + 0.5f * b1h;
            const float iw = fmaxf(fminf(x2, t_x2) - fmaxf(x1, t_x1), 0.0f);
            const float ih = fmaxf(fminf(y2, t_y2) - fmaxf(y1, t_y1), 0.0f);
            const float inter = iw * ih;
            const float pa = (x2 - x1) * (y2 - y1);
            iou1 = inter / (pa + ta - inter);
        }

        const bool sel1 = iou1 > iou0;   // jnp.argmax: first max wins -> strict >
        const float biou = fmaxf(iou0, iou1);
        const float rx = sel1 ? b1x : b0x;
        const float ry = sel1 ? b1y : b0y;
        const float rw = sel1 ? b1w : b0w;
        const float rh = sel1 ? b1h : b0h;
        const float rc = sel1 ? b1c : b0c;

        const float d0 = rx - tx, d1 = ry - ty;
        const float d2 = sqrtf(rw) - sqrtf(tw);
        const float d3 = sqrtf(rh) - sqrtf(th);
        reg += d0 * d0 + d1 * d1 + d2 * d2 + d3 * d3;

        const float dc = rc - biou;
        cont += dc * dc;

        const float* tc = tcls + (size_t)cell * NCLS;
        float csum = 0.0f;
        #pragma unroll
        for (int c = 0; c < NCLS; ++c) {
            const float d = v[CB + NB * 5 + c] - tc[c];
            csum += d * d;
        }
        cls += csum;
    } else {
        const float c0 = v[CB + 4], c1 = v[CB + 9];
        noobj += c0 * c0 + c1 * c1;
    }
}

__launch_bounds__(BLOCK)
__global__ void yolo_loss_kernel(const float* __restrict__ pred,
                                 const float* __restrict__ tbox,
                                 const float* __restrict__ tcls,
                                 const void* __restrict__ mask,
                                 float* __restrict__ ws,
                                 int ncells) {
    const int fmt = ((const int*)ws)[0];
    const int g = blockIdx.x * BLOCK + threadIdx.x;
    const int c0 = g * CELLS_PER_THREAD;

    float reg = 0.0f, cont = 0.0f, noobj = 0.0f, cls = 0.0f;

    if (c0 + CELLS_PER_THREAD <= ncells) {
        // 15 independent dwordx4 loads, issued before anything depends on them.
        float v[60];
        float4* v4 = reinterpret_cast<float4*>(v);
        const float4* prow = reinterpret_cast<const float4*>(pred) + (size_t)g * 15;
        #pragma unroll
        for (int j = 0; j < 15; ++j) v4[j] = prow[j];

        bool m0, m1;
        if (fmt == 2) {
            const float2 mm = reinterpret_cast<const float2*>(mask)[g];
            m0 = mm.x != 0.0f; m1 = mm.y != 0.0f;
        } else if (fmt == 1) {
            const uchar2 mm = reinterpret_cast<const uchar2*>(mask)[g];
            m0 = mm.x != 0; m1 = mm.y != 0;
        } else {
            const int2 mm = reinterpret_cast<const int2*>(mask)[g];
            m0 = mm.x != 0; m1 = mm.y != 0;
        }

        cell_compute<0>(v, tbox, tcls, c0,     m0, reg, cont, noobj, cls);
        cell_compute<30>(v, tbox, tcls, c0 + 1, m1, reg, cont, noobj, cls);
    } else if (c0 < ncells) {
        // scalar tail (not hit when ncells % (BLOCK*2) == 0)
        for (int cell = c0; cell < ncells; ++cell) {
            bool m;
            if (fmt == 2)      m = ((const float*)mask)[cell] != 0.0f;
            else if (fmt == 1) m = ((const unsigned char*)mask)[cell] != 0;
            else               m = ((const int*)mask)[cell] != 0;
            float v[60];
            #pragma unroll
            for (int f = 0; f < 30; ++f) v[f] = pred[(size_t)cell * 30 + f];
            cell_compute<0>(v, tbox, tcls, cell, m, reg, cont, noobj, cls);
        }
    }

    // wave64 reduce
    #pragma unroll
    for (int off = 32; off > 0; off >>= 1) {
        reg   += __shfl_down(reg, off);
        cont  += __shfl_down(cont, off);
        noobj += __shfl_down(noobj, off);
        cls   += __shfl_down(cls, off);
    }

    __shared__ float sred[4][4];  // [wave][counter]
    const int wave = threadIdx.x >> 6;
    const int lane = threadIdx.x & 63;
    if (lane == 0) {
        sred[wave][0] = reg; sred[wave][1] = cont;
        sred[wave][2] = noobj; sred[wave][3] = cls;
    }
    __syncthreads();
    if (threadIdx.x == 0) {
        float r = 0, c = 0, no = 0, cl = 0;
        #pragma unroll
        for (int w = 0; w < 4; ++w) {
            r += sred[w][0]; c += sred[w][1]; no += sred[w][2]; cl += sred[w][3];
        }
        float* slot = ws + 16 + (blockIdx.x & (NSLOTS - 1)) * SLOT_STRIDE;
        atomicAdd(&slot[0], r);
        atomicAdd(&slot[1], c);
        atomicAdd(&slot[2], no);
        atomicAdd(&slot[3], cl);
    }
}

__global__ void yolo_finalize_kernel(const float* __restrict__ ws,
                                     float* __restrict__ out, float inv_n) {
    // one wave: thread t owns slot t
    const int t = threadIdx.x;
    float reg   = ws[16 + t * SLOT_STRIDE + 0];
    float cont  = ws[16 + t * SLOT_STRIDE + 1];
    float noobj = ws[16 + t * SLOT_STRIDE + 2];
    float cls   = ws[16 + t * SLOT_STRIDE + 3];
    #pragma unroll
    for (int off = 32; off > 0; off >>= 1) {
        reg   += __shfl_down(reg, off);
        cont  += __shfl_down(cont, off);
        noobj += __shfl_down(noobj, off);
        cls   += __shfl_down(cls, off);
    }
    if (t == 0) {
        const float total = (5.0f * reg + 0.5f * noobj + cont + cls) * inv_n;
        out[0] = total;
        out[1] = reg;
        out[2] = cont;
        out[3] = noobj;
        out[4] = cls;
    }
}

extern "C" void kernel_launch(void* const* d_in, const int* in_sizes, int n_in,
                              void* d_out, int out_size, void* d_ws, size_t ws_size,
                              hipStream_t stream) {
    const float* pred = (const float*)d_in[0];
    const float* tbox = (const float*)d_in[1];
    const float* tcls = (const float*)d_in[2];
    const void*  mask = d_in[3];
    float* ws  = (float*)d_ws;
    float* out = (float*)d_out;

    const int ncells = in_sizes[3];                 // N * S * S
    const int n_img  = ncells / (GS * GS);          // N
    const float inv_n = 1.0f / (float)n_img;

    yolo_init_kernel<<<1, 256, 0, stream>>>((const unsigned char*)mask, ncells, ws);

    const int grid = (ncells + BLOCK * CELLS_PER_THREAD - 1) / (BLOCK * CELLS_PER_THREAD); // 1568
    yolo_loss_kernel<<<grid, BLOCK, 0, stream>>>(pred, tbox, tcls, mask, ws, ncells);

    yolo_finalize_kernel<<<1, 64, 0, stream>>>(ws, out, inv_n);
}